// Round 22
// baseline (127.587 us; speedup 1.0000x reference)
//
#include <hip/hip_runtime.h>
#include <hip/hip_bf16.h>
#include <cstddef>

#define HW 4096   // 64*64

typedef __attribute__((ext_vector_type(8))) short bf16x8;
typedef __attribute__((ext_vector_type(4))) float f32x4;

__device__ __forceinline__ unsigned short f2b(float v) {
  __hip_bfloat16 b = __float2bfloat16(v);           // round-to-nearest
  return *reinterpret_cast<unsigned short*>(&b);
}
__device__ __forceinline__ float b2f(unsigned short u) {
  return __bfloat162float(*reinterpret_cast<const __hip_bfloat16*>(&u));
}

// ---------------------------------------------------------------------------
// x transpose+convert: xb[n][px][ci] (bf16) from x[n][ci][px] (f32).
// ---------------------------------------------------------------------------
__global__ __launch_bounds__(256) void txp_kernel(const float* __restrict__ x,
                                                  unsigned short* __restrict__ xb) {
  const int n = blockIdx.z, p0 = blockIdx.x * 64, ci0 = blockIdx.y * 64;
  const int t = threadIdx.x;
  __shared__ float Tl[64][65];
#pragma unroll
  for (int pass = 0; pass < 16; ++pass) {
    int ci = pass * 4 + (t >> 6), px = t & 63;
    Tl[ci][px] = x[((size_t)n * 256 + ci0 + ci) * HW + p0 + px];
  }
  __syncthreads();
#pragma unroll
  for (int pass = 0; pass < 16; ++pass) {
    int px = pass * 4 + (t >> 6), ci = t & 63;
    xb[((size_t)n * HW + p0 + px) * 256 + ci0 + ci] = f2b(Tl[ci][px]);
  }
}

// W convert to bf16 ([co][ci] layout kept — it IS the MFMA B fragment layout)
__global__ __launch_bounds__(256) void wcv_kernel(const float* __restrict__ Wq,
                                                  const float* __restrict__ Ws,
                                                  unsigned short* __restrict__ wb) {
  int i = blockIdx.x * 256 + threadIdx.x;   // 0..131071
  const float* W = (i < 65536) ? Wq : Ws;
  wb[i] = f2b(W[i & 65535]);
}

// ---------------------------------------------------------------------------
// MFMA projection, register-blocked (verified, round 21).
// ---------------------------------------------------------------------------
__global__ __launch_bounds__(256) void proj_kernel(
    const unsigned short* __restrict__ xb, const unsigned short* __restrict__ wb,
    const float* __restrict__ bq, const float* __restrict__ bs,
    const float* __restrict__ scale,
    unsigned short* __restrict__ qb, unsigned short* __restrict__ sb) {
  const int row0 = blockIdx.x * 128;
  const int n    = row0 >> 12;          // image
  const int co0  = blockIdx.y * 64;
  const int t    = threadIdx.x;
  const int wv   = t >> 6;
  const int l    = t & 63;
  const float* __restrict__ B = (n == 0) ? bq : bs;
  const unsigned short* __restrict__ Wb = wb + (size_t)(n == 0 ? 0 : 1) * 65536;
  const int prow = row0 + wv * 32;

  const size_t ar0 = ((size_t)prow + (l & 15)) * 256 + (l >> 4) * 8;
  const size_t ar1 = ar0 + 16 * 256;
  size_t br[4];
#pragma unroll
  for (int b = 0; b < 4; ++b)
    br[b] = ((size_t)(co0 + b * 16 + (l & 15))) * 256 + (l >> 4) * 8;

  f32x4 acc[2][4];
#pragma unroll
  for (int a = 0; a < 2; ++a)
#pragma unroll
    for (int b = 0; b < 4; ++b) acc[a][b] = (f32x4){0.f, 0.f, 0.f, 0.f};

#pragma unroll
  for (int kc = 0; kc < 8; ++kc) {
    bf16x8 a0 = *(const bf16x8*)&xb[ar0 + kc * 32];
    bf16x8 a1 = *(const bf16x8*)&xb[ar1 + kc * 32];
#pragma unroll
    for (int b = 0; b < 4; ++b) {
      bf16x8 bb = *(const bf16x8*)&Wb[br[b] + kc * 32];
      acc[0][b] = __builtin_amdgcn_mfma_f32_16x16x32_bf16(a0, bb, acc[0][b], 0, 0, 0);
      acc[1][b] = __builtin_amdgcn_mfma_f32_16x16x32_bf16(a1, bb, acc[1][b], 0, 0, 0);
    }
  }

  float bias[4];
#pragma unroll
  for (int b = 0; b < 4; ++b) bias[b] = B[co0 + b * 16 + (l & 15)];
  const float qsc = scale[0] * 0.17677669529663687f;   // scale * HD^-0.5

#pragma unroll
  for (int a = 0; a < 2; ++a) {
#pragma unroll
    for (int r = 0; r < 4; ++r) {
      float v0 = acc[a][0][r] + bias[0];
      float v1 = acc[a][1][r] + bias[1];
      float v2 = acc[a][2][r] + bias[2];
      float v3 = acc[a][3][r] + bias[3];
      float s0 = v0 * v0 + v1 * v1;
      float s1 = v2 * v2 + v3 * v3;
#pragma unroll
      for (int m = 1; m <= 8; m <<= 1) {
        s0 += __shfl_xor(s0, m);
        s1 += __shfl_xor(s1, m);
      }
      float n0 = fmaxf(sqrtf(s0), 1e-12f);
      float n1 = fmaxf(sqrtf(s1), 1e-12f);
      v0 /= n0; v1 /= n0; v2 /= n1; v3 /= n1;
      const int px = prow + a * 16 + (l >> 4) * 4 + r;
      if (n == 0) {
        size_t o = (size_t)px * 256 + co0 + (l & 15);
        qb[o +  0] = f2b(v0 * qsc);
        qb[o + 16] = f2b(v1 * qsc);
        qb[o + 32] = f2b(v2 * qsc);
        qb[o + 48] = f2b(v3 * qsc);
      } else {
        size_t so = ((size_t)(px - 4096)) * 256 + co0 + (l & 15);  // (n-1)*HW + local
        sb[so +  0] = f2b(v0);
        sb[so + 16] = f2b(v1);
        sb[so + 32] = f2b(v2);
        sb[so + 48] = f2b(v3);
      }
    }
  }
}

// ---------------------------------------------------------------------------
// Patch aggregation (bf16 s input) -> cb (bf16) [8][2560][32], mask[2560].
// ---------------------------------------------------------------------------
__global__ __launch_bounds__(256) void agg_kernel(
    const float* __restrict__ delta, const unsigned short* __restrict__ sb,
    unsigned short* __restrict__ cb, float* __restrict__ mask) {
  const int s = blockIdx.x;
  const int k = blockIdx.y;
  const int t = threadIdx.x;
  __shared__ float fgl[16];
  const int sy = (s >> 4) * 4, sx = (s & 15) * 4;
  if (t < 16) {
    int y0 = (sy + (t >> 2)) * 8, x0 = (sx + (t & 3)) * 8;
    fgl[t] = delta[(size_t)k * 512 * 512 + (size_t)y0 * 512 + x0];
  }
  __syncthreads();
  const int h = t >> 5, d = t & 31;
  float af = 0.f, ab = 0.f;
#pragma unroll
  for (int l = 0; l < 16; ++l) {
    int pix = (sy + (l >> 2)) * 64 + sx + (l & 3);
    float sv = b2f(sb[((size_t)k * HW + pix) * 256 + h * 32 + d]);
    float f = fgl[l];
    af += f * sv;
    ab += (1.f - f) * sv;
  }
  float ssf = af * af, ssb = ab * ab;
#pragma unroll
  for (int m = 1; m <= 16; m <<= 1) {
    ssf += __shfl_xor(ssf, m);
    ssb += __shfl_xor(ssb, m);
  }
  float vf = af / fmaxf(sqrtf(ssf), 1e-12f);
  float vb = ab / fmaxf(sqrtf(ssb), 1e-12f);
  const int jf = k * 512 + s, jb = jf + 256;
  cb[((size_t)h * 2560 + jf) * 32 + d] = f2b(vf);
  cb[((size_t)h * 2560 + jb) * 32 + d] = f2b(vb);
  if (t == 0) {
    float fs = 0.f;
#pragma unroll
    for (int l = 0; l < 16; ++l) fs += fgl[l];
    mask[jf] = (fs < 1.f) ? -1e30f : 0.f;
    mask[jb] = ((16.f - fs) < 1.f) ? -1e30f : 0.f;
  }
}

// ---------------------------------------------------------------------------
// Attention via bf16 MFMA 16x16x32 (verified, round 18).
// ---------------------------------------------------------------------------
__global__ __launch_bounds__(256) void attn_kernel(
    const unsigned short* __restrict__ qb, const unsigned short* __restrict__ cb,
    const float* __restrict__ mask, float* __restrict__ xo) {
  const int t = threadIdx.x;
  const int wv = t >> 6;
  const int l = t & 63;
  const int h = blockIdx.y;
  const int p0 = blockIdx.x * 64 + wv * 16;

  __shared__ float ml[2560];
  for (int i = t; i < 2560; i += 256) ml[i] = mask[i];

  const bf16x8 a = *(const bf16x8*)&qb[(size_t)(p0 + (l & 15)) * 256 + h * 32 + (l >> 4) * 8];
  __syncthreads();

  float num[4] = {0.f, 0.f, 0.f, 0.f}, den[4] = {0.f, 0.f, 0.f, 0.f};
  const size_t cbase = (size_t)h * 2560 * 32 + ((size_t)(l >> 4)) * 8;

  for (int j0 = 0; j0 < 2560; j0 += 16) {
    bf16x8 b = *(const bf16x8*)&cb[cbase + (size_t)(j0 + (l & 15)) * 32];
    f32x4 dacc = {0.f, 0.f, 0.f, 0.f};
    dacc = __builtin_amdgcn_mfma_f32_16x16x32_bf16(a, b, dacc, 0, 0, 0);
    float m = ml[j0 + (l & 15)];
    float cv = ((j0 & 511) < 256) ? 1.f : 0.f;
#pragma unroll
    for (int r = 0; r < 4; ++r) {
      float e = __expf(dacc[r] + m);
      den[r] += e;
      num[r] += cv * e;
    }
  }

#pragma unroll
  for (int r = 0; r < 4; ++r) {
#pragma unroll
    for (int msk = 1; msk <= 8; msk <<= 1) {
      den[r] += __shfl_xor(den[r], msk);
      num[r] += __shfl_xor(num[r], msk);
    }
  }
  if ((l & 15) == 0) {
#pragma unroll
    for (int r = 0; r < 4; ++r) {
      int px = p0 + (l >> 4) * 4 + r;
      xo[(size_t)h * HW + px] = num[r] / den[r];
    }
  }
}

// ---------------------------------------------------------------------------
// conv1 single-pass + bias + block stats. grid (32 y-tiles of 2, 8 co-pairs).
// thread = (co_sub, yr, xi). Group = co0/4 = by/2; stp idx = by*32+bx.
// ---------------------------------------------------------------------------
__global__ __launch_bounds__(256) void conv1_stats(
    const float* __restrict__ in, const float* __restrict__ w,
    const float* __restrict__ b, float* __restrict__ out, float* __restrict__ stp) {
  const int t = threadIdx.x;
  const int y0 = blockIdx.x * 2;
  const int co0 = blockIdx.y * 2;
  __shared__ float Xl[8][6][68];
  __shared__ float Wl[8][25][2];
  __shared__ float sh[256], sh2[256];

  for (int idx = t; idx < 8 * 6 * 68; idx += 256) {
    int ci = idx / 408, rem = idx % 408, pr = rem / 68, pc = rem % 68;
    int iy = y0 + pr - 2, ix = pc - 2;
    float v = 0.f;
    if (iy >= 0 && iy < 64 && ix >= 0 && ix < 64) v = in[(size_t)ci * HW + iy * 64 + ix];
    Xl[ci][pr][pc] = v;
  }
  for (int idx = t; idx < 400; idx += 256) {
    int ci = idx / 50, rem = idx % 50, kk = rem / 2, c = rem % 2;
    Wl[ci][kk][c] = w[(size_t)((co0 + c) * 8 + ci) * 25 + kk];
  }
  __syncthreads();

  const int co_s = t >> 7, yr = (t >> 6) & 1, xi = t & 63;
  float acc = b[co0 + co_s];
#pragma unroll
  for (int ci = 0; ci < 8; ++ci)
#pragma unroll
    for (int ky = 0; ky < 5; ++ky)
#pragma unroll
      for (int kx = 0; kx < 5; ++kx)
        acc += Xl[ci][yr + ky][xi + kx] * Wl[ci][ky * 5 + kx][co_s];
  out[(size_t)(co0 + co_s) * HW + (y0 + yr) * 64 + xi] = acc;

  sh[t] = acc; sh2[t] = acc * acc;
  __syncthreads();
  for (int w2 = 128; w2 > 0; w2 >>= 1) {
    if (t < w2) { sh[t] += sh[t + w2]; sh2[t] += sh2[t + w2]; }
    __syncthreads();
  }
  if (t == 0) {
    int bid = blockIdx.y * 32 + blockIdx.x;
    stp[bid * 2] = sh[0]; stp[bid * 2 + 1] = sh2[0];
  }
}

// ---------------------------------------------------------------------------
// conv2 single-pass with inline GN1+ReLU on staging + bias + block stats.
// grid (16 y-tiles of 4, 16 co-quads). t1: 16ch, 4 groups (cpg=4), bpg=64.
// ---------------------------------------------------------------------------
__global__ __launch_bounds__(256) void conv2_gn(
    const float* __restrict__ t1, const float* __restrict__ stp1,
    const float* __restrict__ g1s, const float* __restrict__ g1b,
    const float* __restrict__ w, const float* __restrict__ b,
    float* __restrict__ t2, float* __restrict__ stp2) {
  const int t = threadIdx.x;
  const int y0 = blockIdx.x * 4;
  const int co0 = blockIdx.y * 4;
  __shared__ float Xl[16][6][66];
  __shared__ float Wl[16][9][4];
  __shared__ float gstat[4][2];
  __shared__ float sh[256], sh2[256];

  {  // finalize 4 input groups; threads g*64+i form wave g
    int g = t >> 6, i = t & 63;
    float s = stp1[(g * 64 + i) * 2], ss = stp1[(g * 64 + i) * 2 + 1];
#pragma unroll
    for (int m = 1; m <= 32; m <<= 1) { s += __shfl_xor(s, m); ss += __shfl_xor(ss, m); }
    if (i == 0) {
      float nn = 4.f * HW;
      float mean = s / nn, var = ss / nn - mean * mean;
      gstat[g][0] = mean;
      gstat[g][1] = 1.f / sqrtf(var + 1e-5f);
    }
  }
  __syncthreads();

  for (int idx = t; idx < 16 * 6 * 66; idx += 256) {
    int ci = idx / 396, rem = idx % 396, pr = rem / 66, pc = rem % 66;
    int iy = y0 + pr - 1, ix = pc - 1;
    float v = 0.f;
    if (iy >= 0 && iy < 64 && ix >= 0 && ix < 64) {
      float raw = t1[(size_t)ci * HW + iy * 64 + ix];
      v = fmaxf((raw - gstat[ci >> 2][0]) * gstat[ci >> 2][1] * g1s[ci] + g1b[ci], 0.f);
    }
    Xl[ci][pr][pc] = v;
  }
  for (int idx = t; idx < 16 * 9 * 4; idx += 256) {
    int ci = idx / 36, rem = idx % 36, kk = rem / 4, c = rem % 4;
    Wl[ci][kk][c] = w[(size_t)((co0 + c) * 16 + ci) * 9 + kk];
  }
  __syncthreads();

  const int xi = t & 63, yr = t >> 6;
  float acc[4] = {b[co0], b[co0 + 1], b[co0 + 2], b[co0 + 3]};
#pragma unroll
  for (int ci = 0; ci < 16; ++ci)
#pragma unroll
    for (int ky = 0; ky < 3; ++ky)
#pragma unroll
      for (int kx = 0; kx < 3; ++kx) {
        float xv = Xl[ci][yr + ky][xi + kx];
        float4 wv = *(const float4*)&Wl[ci][ky * 3 + kx][0];
        acc[0] += xv * wv.x; acc[1] += xv * wv.y;
        acc[2] += xv * wv.z; acc[3] += xv * wv.w;
      }
  const int p = (y0 + yr) * 64 + xi;
  float s = 0.f, ss = 0.f;
#pragma unroll
  for (int c = 0; c < 4; ++c) {
    t2[(size_t)(co0 + c) * HW + p] = acc[c];
    s += acc[c]; ss += acc[c] * acc[c];
  }
  sh[t] = s; sh2[t] = ss;
  __syncthreads();
  for (int w2 = 128; w2 > 0; w2 >>= 1) {
    if (t < w2) { sh[t] += sh[t + w2]; sh2[t] += sh2[t + w2]; }
    __syncthreads();
  }
  if (t == 0) {
    int bid = blockIdx.y * 16 + blockIdx.x;
    stp2[bid * 2] = sh[0]; stp2[bid * 2 + 1] = sh2[0];
  }
}

// ---------------------------------------------------------------------------
// conv3 ci-split (4 x CIC=16) with inline GN2+ReLU. t2: 64ch, cpg=16, bpg=64;
// split z stages channels z*16..z*16+15 = exactly group z. pp[z][co][p].
// ---------------------------------------------------------------------------
__global__ __launch_bounds__(256) void conv3_gn(
    const float* __restrict__ t2, const float* __restrict__ stp2,
    const float* __restrict__ g2s, const float* __restrict__ g2b,
    const float* __restrict__ w, float* __restrict__ pp) {
  const int t = threadIdx.x;
  const int y0 = blockIdx.x * 4;
  const int co0 = blockIdx.y * 8;
  const int z = blockIdx.z;
  const int cb0 = z * 16;
  __shared__ float Xl[16][6][66];
  __shared__ float Wl[16][9][8];
  __shared__ float gm, gr;

  if (t < 64) {  // finalize group z stats (wave 0)
    float s = stp2[(z * 64 + t) * 2], ss = stp2[(z * 64 + t) * 2 + 1];
#pragma unroll
    for (int m = 1; m <= 32; m <<= 1) { s += __shfl_xor(s, m); ss += __shfl_xor(ss, m); }
    if (t == 0) {
      float nn = 16.f * HW;
      float mean = s / nn, var = ss / nn - mean * mean;
      gm = mean;
      gr = 1.f / sqrtf(var + 1e-5f);
    }
  }
  __syncthreads();

  for (int idx = t; idx < 16 * 6 * 66; idx += 256) {
    int ci = idx / 396, rem = idx % 396, pr = rem / 66, pc = rem % 66;
    int iy = y0 + pr - 1, ix = pc - 1;
    float v = 0.f;
    if (iy >= 0 && iy < 64 && ix >= 0 && ix < 64) {
      float raw = t2[(size_t)(cb0 + ci) * HW + iy * 64 + ix];
      v = fmaxf((raw - gm) * gr * g2s[cb0 + ci] + g2b[cb0 + ci], 0.f);
    }
    Xl[ci][pr][pc] = v;
  }
  for (int idx = t; idx < 16 * 9 * 8; idx += 256) {
    int ci = idx / 72, rem = idx % 72, kk = rem / 8, c = rem % 8;
    Wl[ci][kk][c] = w[(size_t)((co0 + c) * 64 + cb0 + ci) * 9 + kk];
  }
  __syncthreads();

  const int xi = t & 63, yr = t >> 6;
  float acc[8] = {0.f, 0.f, 0.f, 0.f, 0.f, 0.f, 0.f, 0.f};
#pragma unroll
  for (int ci = 0; ci < 16; ++ci)
#pragma unroll
    for (int ky = 0; ky < 3; ++ky)
#pragma unroll
      for (int kx = 0; kx < 3; ++kx) {
        float xv = Xl[ci][yr + ky][xi + kx];
        const float4* w4 = (const float4*)&Wl[ci][ky * 3 + kx][0];
        float4 w0 = w4[0], w1 = w4[1];
        acc[0] += xv * w0.x; acc[1] += xv * w0.y; acc[2] += xv * w0.z; acc[3] += xv * w0.w;
        acc[4] += xv * w1.x; acc[5] += xv * w1.y; acc[6] += xv * w1.z; acc[7] += xv * w1.w;
      }
  const int p = (y0 + yr) * 64 + xi;
  float* o = pp + (size_t)z * 128 * HW;
#pragma unroll
  for (int c = 0; c < 8; ++c)
    o[(size_t)(co0 + c) * HW + p] = acc[c];
}

// ---------------------------------------------------------------------------
// merge_stats: out = bias + sum of S partials; per-block {sum, sumsq} -> stp.
// ---------------------------------------------------------------------------
__global__ __launch_bounds__(256) void merge_stats(
    const float* __restrict__ pp, const float* __restrict__ b,
    float* __restrict__ out, float* __restrict__ stp, int S, int CO) {
  __shared__ float sh[256], sh2[256];
  const int t = threadIdx.x;
  const int idx = blockIdx.x * 256 + t;
  const int c = idx >> 12;
  float v = b[c];
  const size_t stride = (size_t)CO * HW;
  for (int s = 0; s < S; ++s) v += pp[(size_t)s * stride + idx];
  out[idx] = v;
  sh[t] = v; sh2[t] = v * v;
  __syncthreads();
  for (int w = 128; w > 0; w >>= 1) {
    if (t < w) { sh[t] += sh[t + w]; sh2[t] += sh2[t + w]; }
    __syncthreads();
  }
  if (t == 0) { stp[blockIdx.x * 2] = sh[0]; stp[blockIdx.x * 2 + 1] = sh2[0]; }
}

// ---------------------------------------------------------------------------
// gn_apply: finalize group stats from stp (bpg blocks/group) + apply + ReLU.
// ---------------------------------------------------------------------------
__global__ __launch_bounds__(256) void gn_apply(
    const float* __restrict__ in, float* __restrict__ out, const float* __restrict__ stp,
    const float* __restrict__ gs, const float* __restrict__ gb, int cpg, int bpg) {
  __shared__ float sh[256], sh2[256];
  const int t = threadIdx.x;
  const int idx = blockIdx.x * 256 + t;
  const int c = idx >> 12;
  const int g = c / cpg;
  float s = 0.f, ss = 0.f;
  for (int i = t; i < bpg; i += 256) {
    s  += stp[(g * bpg + i) * 2];
    ss += stp[(g * bpg + i) * 2 + 1];
  }
  sh[t] = s; sh2[t] = ss;
  __syncthreads();
  for (int w = 128; w > 0; w >>= 1) {
    if (t < w) { sh[t] += sh[t + w]; sh2[t] += sh2[t + w]; }
    __syncthreads();
  }
  const float nn = (float)(cpg * HW);
  const float mean = sh[0] / nn;
  const float var = sh2[0] / nn - mean * mean;
  const float rstd = 1.0f / sqrtf(var + 1e-5f);
  float v = (in[idx] - mean) * rstd * gs[c] + gb[c];
  out[idx] = fmaxf(v, 0.f);
}

// ---------------------------------------------------------------------------
extern "C" void kernel_launch(void* const* d_in, const int* in_sizes, int n_in,
                              void* d_out, int out_size, void* d_ws, size_t ws_size,
                              hipStream_t stream) {
  const float* x     = (const float*)d_in[0];
  const float* delta = (const float*)d_in[1];
  const float* Wq    = (const float*)d_in[2];
  const float* bq    = (const float*)d_in[3];
  const float* Ws    = (const float*)d_in[4];
  const float* bs    = (const float*)d_in[5];
  const float* scale = (const float*)d_in[6];
  const float* c1w = (const float*)d_in[7],  *c1b = (const float*)d_in[8];
  const float* g1s = (const float*)d_in[9],  *g1b = (const float*)d_in[10];
  const float* c2w = (const float*)d_in[11], *c2b = (const float*)d_in[12];
  const float* g2s = (const float*)d_in[13], *g2b = (const float*)d_in[14];
  const float* c3w = (const float*)d_in[15], *c3b = (const float*)d_in[16];
  const float* g3s = (const float*)d_in[17], *g3b = (const float*)d_in[18];

  float* ws = (float*)d_ws;
  unsigned short* sb = (unsigned short*)ws;             // 5,242,880 u16 = 2,621,440 f
  unsigned short* xb = (unsigned short*)(ws + 2621440); // 6,291,456 u16 = 3,145,728 f
  unsigned short* qb = (unsigned short*)(ws + 5767168); // 1,048,576 u16 =   524,288 f
  unsigned short* cb = (unsigned short*)(ws + 6291456); //   655,360 u16 =   327,680 f
  float* mask = ws + 6619136;                           //     2,560
  float* xo   = mask + 2560;                            //    32,768
  float* stp1 = xo + 32768;                             //       512
  float* stp2 = stp1 + 512;                             //       512
  float* stp3 = stp2 + 512;                             //     4,096
  unsigned short* wb = (unsigned short*)(stp3 + 4096);  //   131,072 u16 = 65,536 f
  // conv temps overlay the dead sb+xb region:
  float* pp = ws;                                       // 2,097,152 (4 x 128 x 4096)
  float* t1 = ws + 2097152;                             //    65,536
  float* t2 = t1 + 65536;                               //   262,144
  float* t3 = t2 + 262144;                              //   524,288  (ends 2,949,120)
  // total ~= 25.7 MB

  txp_kernel<<<dim3(64, 4, 6), 256, 0, stream>>>(x, xb);
  wcv_kernel<<<512, 256, 0, stream>>>(Wq, Ws, wb);
  proj_kernel<<<dim3(192, 4), 256, 0, stream>>>(xb, wb, bq, bs, scale, qb, sb);
  agg_kernel<<<dim3(256, 5), 256, 0, stream>>>(delta, sb, cb, mask);
  attn_kernel<<<dim3(64, 8), 256, 0, stream>>>(qb, cb, mask, xo);

  conv1_stats<<<dim3(32, 8), 256, 0, stream>>>(xo, c1w, c1b, t1, stp1);
  conv2_gn<<<dim3(16, 16), 256, 0, stream>>>(t1, stp1, g1s, g1b, c2w, c2b, t2, stp2);
  conv3_gn<<<dim3(16, 16, 4), 256, 0, stream>>>(t2, stp2, g2s, g2b, c3w, pp);
  merge_stats<<<2048, 256, 0, stream>>>(pp, c3b, t3, stp3, 4, 128);
  gn_apply<<<2048, 256, 0, stream>>>(t3, (float*)d_out, stp3, g3s, g3b, 32, 512);
}

// Round 23
// 122.317 us; speedup vs baseline: 1.0431x; 1.0431x over previous
//
#include <hip/hip_runtime.h>
#include <hip/hip_bf16.h>
#include <cstddef>

#define HW 4096   // 64*64

typedef __attribute__((ext_vector_type(8))) short bf16x8;
typedef __attribute__((ext_vector_type(4))) float f32x4;

__device__ __forceinline__ unsigned short f2b(float v) {
  __hip_bfloat16 b = __float2bfloat16(v);           // round-to-nearest
  return *reinterpret_cast<unsigned short*>(&b);
}
__device__ __forceinline__ float b2f(unsigned short u) {
  return __bfloat162float(*reinterpret_cast<const __hip_bfloat16*>(&u));
}

// W convert to bf16 ([co][ci] layout kept — it IS the MFMA B fragment layout)
__global__ __launch_bounds__(256) void wcv_kernel(const float* __restrict__ Wq,
                                                  const float* __restrict__ Ws,
                                                  unsigned short* __restrict__ wb) {
  int i = blockIdx.x * 256 + threadIdx.x;   // 0..131071
  const float* W = (i < 65536) ? Wq : Ws;
  wb[i] = f2b(W[i & 65535]);
}

// ---------------------------------------------------------------------------
// MFMA projection with fused x->bf16 transpose (A staged in fragment order).
// block = 32 px x 256 co, 4 waves split by co (wave wv: co wv*64..wv*64+63).
// grid = 24576/32 = 768. A-tile read from f32 x ONCE per block, shared by all
// waves via LDS; B rows stream from global (L2-resident, 128 KB total).
// Epilogue: bias + per-head l2norm via shfl over the 16 col-lanes (verified).
// ---------------------------------------------------------------------------
__global__ __launch_bounds__(256) void proj_kernel(
    const float* __restrict__ x, const unsigned short* __restrict__ wb,
    const float* __restrict__ bq, const float* __restrict__ bs,
    const float* __restrict__ scale,
    unsigned short* __restrict__ qb, unsigned short* __restrict__ sb) {
  const int row0 = blockIdx.x * 32;     // global row (0..24575)
  const int n    = row0 >> 12;          // image
  const int pxg  = row0 & 4095;         // local pixel base
  const int t    = threadIdx.x;
  const int wv   = t >> 6;
  const int l    = t & 63;
  const int co0  = wv * 64;
  const float* __restrict__ B = (n == 0) ? bq : bs;
  const unsigned short* __restrict__ Wb = wb + (size_t)(n == 0 ? 0 : 1) * 65536;

  // A fragments: [a(px-half)][kc][lane][elem] — lane-contiguous 16B reads
  __shared__ unsigned short Af[2][8][64][8];   // 16 KB

#pragma unroll
  for (int pass = 0; pass < 32; ++pass) {
    int idx = pass * 256 + t;           // 8192 = 32px * 256ci
    int px = idx & 31, ci = idx >> 5;
    float v = x[((size_t)n * 256 + ci) * HW + pxg + px];
    Af[px >> 4][ci >> 5][((ci >> 3) & 3) * 16 + (px & 15)][ci & 7] = f2b(v);
  }
  __syncthreads();

  size_t br[4];
#pragma unroll
  for (int b = 0; b < 4; ++b)
    br[b] = ((size_t)(co0 + b * 16 + (l & 15))) * 256 + (l >> 4) * 8;

  f32x4 acc[2][4];
#pragma unroll
  for (int a = 0; a < 2; ++a)
#pragma unroll
    for (int b = 0; b < 4; ++b) acc[a][b] = (f32x4){0.f, 0.f, 0.f, 0.f};

#pragma unroll
  for (int kc = 0; kc < 8; ++kc) {
    bf16x8 a0 = *(const bf16x8*)&Af[0][kc][l][0];
    bf16x8 a1 = *(const bf16x8*)&Af[1][kc][l][0];
#pragma unroll
    for (int b = 0; b < 4; ++b) {
      bf16x8 bb = *(const bf16x8*)&Wb[br[b] + kc * 32];
      acc[0][b] = __builtin_amdgcn_mfma_f32_16x16x32_bf16(a0, bb, acc[0][b], 0, 0, 0);
      acc[1][b] = __builtin_amdgcn_mfma_f32_16x16x32_bf16(a1, bb, acc[1][b], 0, 0, 0);
    }
  }

  float bias[4];
#pragma unroll
  for (int b = 0; b < 4; ++b) bias[b] = B[co0 + b * 16 + (l & 15)];
  const float qsc = scale[0] * 0.17677669529663687f;   // scale * HD^-0.5

  // D: px = pxg + a*16 + (l>>4)*4 + r ; co = co0 + b*16 + (l&15)
  // heads: b{0,1} -> 2wv, b{2,3} -> 2wv+1 (co0 = 64*wv)
#pragma unroll
  for (int a = 0; a < 2; ++a) {
#pragma unroll
    for (int r = 0; r < 4; ++r) {
      float v0 = acc[a][0][r] + bias[0];
      float v1 = acc[a][1][r] + bias[1];
      float v2 = acc[a][2][r] + bias[2];
      float v3 = acc[a][3][r] + bias[3];
      float s0 = v0 * v0 + v1 * v1;
      float s1 = v2 * v2 + v3 * v3;
#pragma unroll
      for (int m = 1; m <= 8; m <<= 1) {
        s0 += __shfl_xor(s0, m);
        s1 += __shfl_xor(s1, m);
      }
      float n0 = fmaxf(sqrtf(s0), 1e-12f);
      float n1 = fmaxf(sqrtf(s1), 1e-12f);
      v0 /= n0; v1 /= n0; v2 /= n1; v3 /= n1;
      const int pix = pxg + a * 16 + (l >> 4) * 4 + r;   // local pixel
      if (n == 0) {
        size_t o = (size_t)pix * 256 + co0 + (l & 15);
        qb[o +  0] = f2b(v0 * qsc);
        qb[o + 16] = f2b(v1 * qsc);
        qb[o + 32] = f2b(v2 * qsc);
        qb[o + 48] = f2b(v3 * qsc);
      } else {
        size_t so = ((size_t)(n - 1) * HW + pix) * 256 + co0 + (l & 15);
        sb[so +  0] = f2b(v0);
        sb[so + 16] = f2b(v1);
        sb[so + 32] = f2b(v2);
        sb[so + 48] = f2b(v3);
      }
    }
  }
}

// ---------------------------------------------------------------------------
// Patch aggregation (bf16 s input) -> cb (bf16) [8][2560][32], mask[2560].
// ---------------------------------------------------------------------------
__global__ __launch_bounds__(256) void agg_kernel(
    const float* __restrict__ delta, const unsigned short* __restrict__ sb,
    unsigned short* __restrict__ cb, float* __restrict__ mask) {
  const int s = blockIdx.x;
  const int k = blockIdx.y;
  const int t = threadIdx.x;
  __shared__ float fgl[16];
  const int sy = (s >> 4) * 4, sx = (s & 15) * 4;
  if (t < 16) {
    int y0 = (sy + (t >> 2)) * 8, x0 = (sx + (t & 3)) * 8;
    fgl[t] = delta[(size_t)k * 512 * 512 + (size_t)y0 * 512 + x0];
  }
  __syncthreads();
  const int h = t >> 5, d = t & 31;
  float af = 0.f, ab = 0.f;
#pragma unroll
  for (int l = 0; l < 16; ++l) {
    int pix = (sy + (l >> 2)) * 64 + sx + (l & 3);
    float sv = b2f(sb[((size_t)k * HW + pix) * 256 + h * 32 + d]);
    float f = fgl[l];
    af += f * sv;
    ab += (1.f - f) * sv;
  }
  float ssf = af * af, ssb = ab * ab;
#pragma unroll
  for (int m = 1; m <= 16; m <<= 1) {
    ssf += __shfl_xor(ssf, m);
    ssb += __shfl_xor(ssb, m);
  }
  float vf = af / fmaxf(sqrtf(ssf), 1e-12f);
  float vb = ab / fmaxf(sqrtf(ssb), 1e-12f);
  const int jf = k * 512 + s, jb = jf + 256;
  cb[((size_t)h * 2560 + jf) * 32 + d] = f2b(vf);
  cb[((size_t)h * 2560 + jb) * 32 + d] = f2b(vb);
  if (t == 0) {
    float fs = 0.f;
#pragma unroll
    for (int l = 0; l < 16; ++l) fs += fgl[l];
    mask[jf] = (fs < 1.f) ? -1e30f : 0.f;
    mask[jb] = ((16.f - fs) < 1.f) ? -1e30f : 0.f;
  }
}

// ---------------------------------------------------------------------------
// Attention via bf16 MFMA 16x16x32 (verified, round 18).
// ---------------------------------------------------------------------------
__global__ __launch_bounds__(256) void attn_kernel(
    const unsigned short* __restrict__ qb, const unsigned short* __restrict__ cb,
    const float* __restrict__ mask, float* __restrict__ xo) {
  const int t = threadIdx.x;
  const int wv = t >> 6;
  const int l = t & 63;
  const int h = blockIdx.y;
  const int p0 = blockIdx.x * 64 + wv * 16;

  __shared__ float ml[2560];
  for (int i = t; i < 2560; i += 256) ml[i] = mask[i];

  const bf16x8 a = *(const bf16x8*)&qb[(size_t)(p0 + (l & 15)) * 256 + h * 32 + (l >> 4) * 8];
  __syncthreads();

  float num[4] = {0.f, 0.f, 0.f, 0.f}, den[4] = {0.f, 0.f, 0.f, 0.f};
  const size_t cbase = (size_t)h * 2560 * 32 + ((size_t)(l >> 4)) * 8;

  for (int j0 = 0; j0 < 2560; j0 += 16) {
    bf16x8 b = *(const bf16x8*)&cb[cbase + (size_t)(j0 + (l & 15)) * 32];
    f32x4 dacc = {0.f, 0.f, 0.f, 0.f};
    dacc = __builtin_amdgcn_mfma_f32_16x16x32_bf16(a, b, dacc, 0, 0, 0);
    float m = ml[j0 + (l & 15)];
    float cv = ((j0 & 511) < 256) ? 1.f : 0.f;
#pragma unroll
    for (int r = 0; r < 4; ++r) {
      float e = __expf(dacc[r] + m);
      den[r] += e;
      num[r] += cv * e;
    }
  }

#pragma unroll
  for (int r = 0; r < 4; ++r) {
#pragma unroll
    for (int msk = 1; msk <= 8; msk <<= 1) {
      den[r] += __shfl_xor(den[r], msk);
      num[r] += __shfl_xor(num[r], msk);
    }
  }
  if ((l & 15) == 0) {
#pragma unroll
    for (int r = 0; r < 4; ++r) {
      int px = p0 + (l >> 4) * 4 + r;
      xo[(size_t)h * HW + px] = num[r] / den[r];
    }
  }
}

// ---------------------------------------------------------------------------
// conv1 single-pass + bias + block stats (verified, round 22).
// ---------------------------------------------------------------------------
__global__ __launch_bounds__(256) void conv1_stats(
    const float* __restrict__ in, const float* __restrict__ w,
    const float* __restrict__ b, float* __restrict__ out, float* __restrict__ stp) {
  const int t = threadIdx.x;
  const int y0 = blockIdx.x * 2;
  const int co0 = blockIdx.y * 2;
  __shared__ float Xl[8][6][68];
  __shared__ float Wl[8][25][2];
  __shared__ float sh[256], sh2[256];

  for (int idx = t; idx < 8 * 6 * 68; idx += 256) {
    int ci = idx / 408, rem = idx % 408, pr = rem / 68, pc = rem % 68;
    int iy = y0 + pr - 2, ix = pc - 2;
    float v = 0.f;
    if (iy >= 0 && iy < 64 && ix >= 0 && ix < 64) v = in[(size_t)ci * HW + iy * 64 + ix];
    Xl[ci][pr][pc] = v;
  }
  for (int idx = t; idx < 400; idx += 256) {
    int ci = idx / 50, rem = idx % 50, kk = rem / 2, c = rem % 2;
    Wl[ci][kk][c] = w[(size_t)((co0 + c) * 8 + ci) * 25 + kk];
  }
  __syncthreads();

  const int co_s = t >> 7, yr = (t >> 6) & 1, xi = t & 63;
  float acc = b[co0 + co_s];
#pragma unroll
  for (int ci = 0; ci < 8; ++ci)
#pragma unroll
    for (int ky = 0; ky < 5; ++ky)
#pragma unroll
      for (int kx = 0; kx < 5; ++kx)
        acc += Xl[ci][yr + ky][xi + kx] * Wl[ci][ky * 5 + kx][co_s];
  out[(size_t)(co0 + co_s) * HW + (y0 + yr) * 64 + xi] = acc;

  sh[t] = acc; sh2[t] = acc * acc;
  __syncthreads();
  for (int w2 = 128; w2 > 0; w2 >>= 1) {
    if (t < w2) { sh[t] += sh[t + w2]; sh2[t] += sh2[t + w2]; }
    __syncthreads();
  }
  if (t == 0) {
    int bid = blockIdx.y * 32 + blockIdx.x;
    stp[bid * 2] = sh[0]; stp[bid * 2 + 1] = sh2[0];
  }
}

// ---------------------------------------------------------------------------
// conv2 single-pass with inline GN1+ReLU + bias + block stats (round 22).
// ---------------------------------------------------------------------------
__global__ __launch_bounds__(256) void conv2_gn(
    const float* __restrict__ t1, const float* __restrict__ stp1,
    const float* __restrict__ g1s, const float* __restrict__ g1b,
    const float* __restrict__ w, const float* __restrict__ b,
    float* __restrict__ t2, float* __restrict__ stp2) {
  const int t = threadIdx.x;
  const int y0 = blockIdx.x * 4;
  const int co0 = blockIdx.y * 4;
  __shared__ float Xl[16][6][66];
  __shared__ float Wl[16][9][4];
  __shared__ float gstat[4][2];
  __shared__ float sh[256], sh2[256];

  {
    int g = t >> 6, i = t & 63;
    float s = stp1[(g * 64 + i) * 2], ss = stp1[(g * 64 + i) * 2 + 1];
#pragma unroll
    for (int m = 1; m <= 32; m <<= 1) { s += __shfl_xor(s, m); ss += __shfl_xor(ss, m); }
    if (i == 0) {
      float nn = 4.f * HW;
      float mean = s / nn, var = ss / nn - mean * mean;
      gstat[g][0] = mean;
      gstat[g][1] = 1.f / sqrtf(var + 1e-5f);
    }
  }
  __syncthreads();

  for (int idx = t; idx < 16 * 6 * 66; idx += 256) {
    int ci = idx / 396, rem = idx % 396, pr = rem / 66, pc = rem % 66;
    int iy = y0 + pr - 1, ix = pc - 1;
    float v = 0.f;
    if (iy >= 0 && iy < 64 && ix >= 0 && ix < 64) {
      float raw = t1[(size_t)ci * HW + iy * 64 + ix];
      v = fmaxf((raw - gstat[ci >> 2][0]) * gstat[ci >> 2][1] * g1s[ci] + g1b[ci], 0.f);
    }
    Xl[ci][pr][pc] = v;
  }
  for (int idx = t; idx < 16 * 9 * 4; idx += 256) {
    int ci = idx / 36, rem = idx % 36, kk = rem / 4, c = rem % 4;
    Wl[ci][kk][c] = w[(size_t)((co0 + c) * 16 + ci) * 9 + kk];
  }
  __syncthreads();

  const int xi = t & 63, yr = t >> 6;
  float acc[4] = {b[co0], b[co0 + 1], b[co0 + 2], b[co0 + 3]};
#pragma unroll
  for (int ci = 0; ci < 16; ++ci)
#pragma unroll
    for (int ky = 0; ky < 3; ++ky)
#pragma unroll
      for (int kx = 0; kx < 3; ++kx) {
        float xv = Xl[ci][yr + ky][xi + kx];
        float4 wv = *(const float4*)&Wl[ci][ky * 3 + kx][0];
        acc[0] += xv * wv.x; acc[1] += xv * wv.y;
        acc[2] += xv * wv.z; acc[3] += xv * wv.w;
      }
  const int p = (y0 + yr) * 64 + xi;
  float s = 0.f, ss = 0.f;
#pragma unroll
  for (int c = 0; c < 4; ++c) {
    t2[(size_t)(co0 + c) * HW + p] = acc[c];
    s += acc[c]; ss += acc[c] * acc[c];
  }
  sh[t] = s; sh2[t] = ss;
  __syncthreads();
  for (int w2 = 128; w2 > 0; w2 >>= 1) {
    if (t < w2) { sh[t] += sh[t + w2]; sh2[t] += sh2[t + w2]; }
    __syncthreads();
  }
  if (t == 0) {
    int bid = blockIdx.y * 16 + blockIdx.x;
    stp2[bid * 2] = sh[0]; stp2[bid * 2 + 1] = sh2[0];
  }
}

// ---------------------------------------------------------------------------
// conv3 ci-split (4 x CIC=16) with inline GN2+ReLU (round 22).
// ---------------------------------------------------------------------------
__global__ __launch_bounds__(256) void conv3_gn(
    const float* __restrict__ t2, const float* __restrict__ stp2,
    const float* __restrict__ g2s, const float* __restrict__ g2b,
    const float* __restrict__ w, float* __restrict__ pp) {
  const int t = threadIdx.x;
  const int y0 = blockIdx.x * 4;
  const int co0 = blockIdx.y * 8;
  const int z = blockIdx.z;
  const int cb0 = z * 16;
  __shared__ float Xl[16][6][66];
  __shared__ float Wl[16][9][8];
  __shared__ float gm, gr;

  if (t < 64) {
    float s = stp2[(z * 64 + t) * 2], ss = stp2[(z * 64 + t) * 2 + 1];
#pragma unroll
    for (int m = 1; m <= 32; m <<= 1) { s += __shfl_xor(s, m); ss += __shfl_xor(ss, m); }
    if (t == 0) {
      float nn = 16.f * HW;
      float mean = s / nn, var = ss / nn - mean * mean;
      gm = mean;
      gr = 1.f / sqrtf(var + 1e-5f);
    }
  }
  __syncthreads();

  for (int idx = t; idx < 16 * 6 * 66; idx += 256) {
    int ci = idx / 396, rem = idx % 396, pr = rem / 66, pc = rem % 66;
    int iy = y0 + pr - 1, ix = pc - 1;
    float v = 0.f;
    if (iy >= 0 && iy < 64 && ix >= 0 && ix < 64) {
      float raw = t2[(size_t)(cb0 + ci) * HW + iy * 64 + ix];
      v = fmaxf((raw - gm) * gr * g2s[cb0 + ci] + g2b[cb0 + ci], 0.f);
    }
    Xl[ci][pr][pc] = v;
  }
  for (int idx = t; idx < 16 * 9 * 8; idx += 256) {
    int ci = idx / 72, rem = idx % 72, kk = rem / 8, c = rem % 8;
    Wl[ci][kk][c] = w[(size_t)((co0 + c) * 64 + cb0 + ci) * 9 + kk];
  }
  __syncthreads();

  const int xi = t & 63, yr = t >> 6;
  float acc[8] = {0.f, 0.f, 0.f, 0.f, 0.f, 0.f, 0.f, 0.f};
#pragma unroll
  for (int ci = 0; ci < 16; ++ci)
#pragma unroll
    for (int ky = 0; ky < 3; ++ky)
#pragma unroll
      for (int kx = 0; kx < 3; ++kx) {
        float xv = Xl[ci][yr + ky][xi + kx];
        const float4* w4 = (const float4*)&Wl[ci][ky * 3 + kx][0];
        float4 w0 = w4[0], w1 = w4[1];
        acc[0] += xv * w0.x; acc[1] += xv * w0.y; acc[2] += xv * w0.z; acc[3] += xv * w0.w;
        acc[4] += xv * w1.x; acc[5] += xv * w1.y; acc[6] += xv * w1.z; acc[7] += xv * w1.w;
      }
  const int p = (y0 + yr) * 64 + xi;
  float* o = pp + (size_t)z * 128 * HW;
#pragma unroll
  for (int c = 0; c < 8; ++c)
    o[(size_t)(co0 + c) * HW + p] = acc[c];
}

// ---------------------------------------------------------------------------
// merge_stats: out = bias + sum of S partials; per-block {sum, sumsq} -> stp.
// ---------------------------------------------------------------------------
__global__ __launch_bounds__(256) void merge_stats(
    const float* __restrict__ pp, const float* __restrict__ b,
    float* __restrict__ out, float* __restrict__ stp, int S, int CO) {
  __shared__ float sh[256], sh2[256];
  const int t = threadIdx.x;
  const int idx = blockIdx.x * 256 + t;
  const int c = idx >> 12;
  float v = b[c];
  const size_t stride = (size_t)CO * HW;
  for (int s = 0; s < S; ++s) v += pp[(size_t)s * stride + idx];
  out[idx] = v;
  sh[t] = v; sh2[t] = v * v;
  __syncthreads();
  for (int w = 128; w > 0; w >>= 1) {
    if (t < w) { sh[t] += sh[t + w]; sh2[t] += sh2[t + w]; }
    __syncthreads();
  }
  if (t == 0) { stp[blockIdx.x * 2] = sh[0]; stp[blockIdx.x * 2 + 1] = sh2[0]; }
}

// ---------------------------------------------------------------------------
// gn_apply: finalize group stats from stp (bpg blocks/group) + apply + ReLU.
// ---------------------------------------------------------------------------
__global__ __launch_bounds__(256) void gn_apply(
    const float* __restrict__ in, float* __restrict__ out, const float* __restrict__ stp,
    const float* __restrict__ gs, const float* __restrict__ gb, int cpg, int bpg) {
  __shared__ float sh[256], sh2[256];
  const int t = threadIdx.x;
  const int idx = blockIdx.x * 256 + t;
  const int c = idx >> 12;
  const int g = c / cpg;
  float s = 0.f, ss = 0.f;
  for (int i = t; i < bpg; i += 256) {
    s  += stp[(g * bpg + i) * 2];
    ss += stp[(g * bpg + i) * 2 + 1];
  }
  sh[t] = s; sh2[t] = ss;
  __syncthreads();
  for (int w = 128; w > 0; w >>= 1) {
    if (t < w) { sh[t] += sh[t + w]; sh2[t] += sh2[t + w]; }
    __syncthreads();
  }
  const float nn = (float)(cpg * HW);
  const float mean = sh[0] / nn;
  const float var = sh2[0] / nn - mean * mean;
  const float rstd = 1.0f / sqrtf(var + 1e-5f);
  float v = (in[idx] - mean) * rstd * gs[c] + gb[c];
  out[idx] = fmaxf(v, 0.f);
}

// ---------------------------------------------------------------------------
extern "C" void kernel_launch(void* const* d_in, const int* in_sizes, int n_in,
                              void* d_out, int out_size, void* d_ws, size_t ws_size,
                              hipStream_t stream) {
  const float* x     = (const float*)d_in[0];
  const float* delta = (const float*)d_in[1];
  const float* Wq    = (const float*)d_in[2];
  const float* bq    = (const float*)d_in[3];
  const float* Ws    = (const float*)d_in[4];
  const float* bs    = (const float*)d_in[5];
  const float* scale = (const float*)d_in[6];
  const float* c1w = (const float*)d_in[7],  *c1b = (const float*)d_in[8];
  const float* g1s = (const float*)d_in[9],  *g1b = (const float*)d_in[10];
  const float* c2w = (const float*)d_in[11], *c2b = (const float*)d_in[12];
  const float* g2s = (const float*)d_in[13], *g2b = (const float*)d_in[14];
  const float* c3w = (const float*)d_in[15], *c3b = (const float*)d_in[16];
  const float* g3s = (const float*)d_in[17], *g3b = (const float*)d_in[18];

  float* ws = (float*)d_ws;
  unsigned short* sb = (unsigned short*)ws;             // 5,242,880 u16 = 2,621,440 f
  unsigned short* qb = (unsigned short*)(ws + 5767168); // 1,048,576 u16 =   524,288 f
  unsigned short* cb = (unsigned short*)(ws + 6291456); //   655,360 u16 =   327,680 f
  float* mask = ws + 6619136;                           //     2,560
  float* xo   = mask + 2560;                            //    32,768
  float* stp1 = xo + 32768;                             //       512
  float* stp2 = stp1 + 512;                             //       512
  float* stp3 = stp2 + 512;                             //     4,096
  unsigned short* wb = (unsigned short*)(stp3 + 4096);  //   131,072 u16 = 65,536 f
  // conv temps overlay the dead sb region:
  float* pp = ws;                                       // 2,097,152 (4 x 128 x 4096)
  float* t1 = ws + 2097152;                             //    65,536
  float* t2 = t1 + 65536;                               //   262,144
  float* t3 = t2 + 262144;                              //   524,288  (ends 2,949,120)
  // total ~= 25.7 MB

  wcv_kernel<<<512, 256, 0, stream>>>(Wq, Ws, wb);
  proj_kernel<<<768, 256, 0, stream>>>(x, wb, bq, bs, scale, qb, sb);
  agg_kernel<<<dim3(256, 5), 256, 0, stream>>>(delta, sb, cb, mask);
  attn_kernel<<<dim3(64, 8), 256, 0, stream>>>(qb, cb, mask, xo);

  conv1_stats<<<dim3(32, 8), 256, 0, stream>>>(xo, c1w, c1b, t1, stp1);
  conv2_gn<<<dim3(16, 16), 256, 0, stream>>>(t1, stp1, g1s, g1b, c2w, c2b, t2, stp2);
  conv3_gn<<<dim3(16, 16, 4), 256, 0, stream>>>(t2, stp2, g2s, g2b, c3w, pp);
  merge_stats<<<2048, 256, 0, stream>>>(pp, c3b, t3, stp3, 4, 128);
  gn_apply<<<2048, 256, 0, stream>>>(t3, (float*)d_out, stp3, g3s, g3b, 32, 512);
}